// Round 4
// baseline (112312.378 us; speedup 1.0000x reference)
//
#include <hip/hip_runtime.h>
#include <hip/hip_bf16.h>
#include <cstdint>
#include <cstddef>

#define VOCAB 10000
#define EMB   1024
#define HID   1024
#define BATCH 32
#define SEQ   256
#define ROWS  (SEQ*BATCH)   // 8192
#define SNBLK 16            // scan workers; 64 cols each
#define PB    128           // ctrl: published-xcc base (ints)
#define FB    1024          // ctrl: step-flag base (ints), stride 32

typedef __attribute__((ext_vector_type(8))) short short8;
typedef __attribute__((ext_vector_type(4))) float f32x4;

static __device__ __forceinline__ unsigned short f2bf(float f){
  unsigned int u = __builtin_bit_cast(unsigned int, f);
  u += 0x7fffu + ((u >> 16) & 1u);
  return (unsigned short)(u >> 16);
}

// sc0-only load: bypass L1, hit the (shared, same-XCD) L2. NOT sc1 — stays in L2.
static __device__ __forceinline__ int load_flag_sc0(const int* p){
  int v;
  asm volatile("global_load_dword %0, %1, off sc0\n\t"
               "s_waitcnt vmcnt(0)"
               : "=v"(v) : "v"(p) : "memory");
  return v;
}

// ---------- transpose-convert: fp32 src[K][N] -> bf16 dst[N][K] ----------
__global__ void k_transpose(const float* __restrict__ src, unsigned short* __restrict__ dst,
                            int K, int N){
  __shared__ unsigned short tile[64][65];
  int n0 = blockIdx.x * 64, k0 = blockIdx.y * 64;
  int tid = threadIdx.x;
  #pragma unroll
  for (int it = 0; it < 16; ++it){
    int e = tid + it*256;
    int i = e >> 6, j = e & 63;
    float v = 0.f;
    if (k0 + i < K && n0 + j < N) v = src[(size_t)(k0+i)*N + n0 + j];
    tile[j][i] = f2bf(v);
  }
  __syncthreads();
  #pragma unroll
  for (int it = 0; it < 16; ++it){
    int e = tid + it*256;
    int r = e >> 6, c = e & 63;
    if (n0 + r < N && k0 + c < K)
      dst[(size_t)(n0+r)*K + k0 + c] = tile[r][c];
  }
}

// ---------- embedding gather + fp32->bf16 ----------
__global__ void k_gather(const int* __restrict__ seq, const float* __restrict__ emb,
                         unsigned short* __restrict__ X){
  int r = blockIdx.x;                 // r = t*32 + b
  int t = r >> 5, b = r & 31;
  int idx = seq[b*SEQ + t];
  const float4* s = (const float4*)(emb + (size_t)idx * EMB);
  float4 v = s[threadIdx.x];
  ushort4 o;
  o.x = f2bf(v.x); o.y = f2bf(v.y); o.z = f2bf(v.z); o.w = f2bf(v.w);
  ((ushort4*)(X + (size_t)r * EMB))[threadIdx.x] = o;
}

// ---------- GEMM: C[M][ldc] = A[M][K](bf16) * BT[Npad][K](bf16)^T + bias ----------
template<bool OUT_BF16>
__global__ __launch_bounds__(256) void k_gemm_bt(
    const unsigned short* __restrict__ A,
    const unsigned short* __restrict__ BT,
    const float* __restrict__ bias,
    void* __restrict__ C, int M, int Nreal, int K, int ldc){
  __shared__ __align__(16) unsigned short As[128][40];
  __shared__ __align__(16) unsigned short Bs[128][40];
  int tid  = threadIdx.x;
  int lane = tid & 63, wid = tid >> 6;
  int wr = (wid >> 1) * 64, wc = (wid & 1) * 64;
  int m0 = blockIdx.y * 128, n0 = blockIdx.x * 128;
  int la = lane & 15, ko = (lane >> 4) * 8;
  f32x4 acc[4][4] = {};
  for (int k0 = 0; k0 < K; k0 += 32){
    #pragma unroll
    for (int q = tid; q < 512; q += 256){
      int row = q >> 2, kc = (q & 3) * 8;
      *(uint4*)&As[row][kc] = *(const uint4*)(A  + (size_t)(m0+row)*K + k0 + kc);
      *(uint4*)&Bs[row][kc] = *(const uint4*)(BT + (size_t)(n0+row)*K + k0 + kc);
    }
    __syncthreads();
    short8 av[4], bv[4];
    #pragma unroll
    for (int f = 0; f < 4; ++f){
      av[f] = *(const short8*)&As[wr + f*16 + la][ko];
      bv[f] = *(const short8*)&Bs[wc + f*16 + la][ko];
    }
    #pragma unroll
    for (int mf = 0; mf < 4; ++mf)
      #pragma unroll
      for (int nf = 0; nf < 4; ++nf)
        acc[mf][nf] = __builtin_amdgcn_mfma_f32_16x16x32_bf16(av[mf], bv[nf], acc[mf][nf], 0, 0, 0);
    __syncthreads();
  }
  int dr = (lane >> 4) * 4, dc = lane & 15;
  #pragma unroll
  for (int mf = 0; mf < 4; ++mf){
    #pragma unroll
    for (int nf = 0; nf < 4; ++nf){
      int col = n0 + wc + nf*16 + dc;
      if (col >= Nreal) continue;
      float bb = bias[col];
      #pragma unroll
      for (int rg = 0; rg < 4; ++rg){
        int row = m0 + wr + mf*16 + dr + rg;
        float v = acc[mf][nf][rg] + bb;
        if (OUT_BF16) ((unsigned short*)C)[(size_t)row*ldc + col] = f2bf(v);
        else          ((float*)C)[(size_t)row*ldc + col] = v;
      }
    }
  }
}

// ---------- persistent scan: 16 workers elected onto ONE XCD; pure-L2 flag sync ----------
__global__ __launch_bounds__(256, 1) void k_scan(
    const unsigned short* __restrict__ UT,   // [HID][HID] bf16, UT[n][k]
    const float* __restrict__ G0,            // [ROWS][HID] fp32 (includes b_gate)
    unsigned short* __restrict__ Hfull,      // [(32+ROWS)][HID] bf16, rows 0..31 zeroed
    int* ctrl){
  __shared__ float red[2][32][64];
  __shared__ int s_slot, s_fast;
  const int tid  = threadIdx.x;
  const int lane = tid & 63, wid = tid >> 6;

  // ---- election: prefer blocks on the leader XCD (CAS winner's XCD) ----
  if (tid == 0){
    int xcc;
    asm volatile("s_getreg_b32 %0, hwreg(HW_REG_XCC_ID)" : "=s"(xcc));
    xcc &= 0xff;
    int expected = 0;
    __hip_atomic_compare_exchange_strong(&ctrl[0], &expected, xcc + 1,
        __ATOMIC_ACQ_REL, __ATOMIC_ACQUIRE, __HIP_MEMORY_SCOPE_AGENT);
    int lead = (expected == 0) ? xcc : expected - 1;
    int ticket = -1;
    if (xcc == lead){
      ticket = __hip_atomic_fetch_add(&ctrl[32], 1, __ATOMIC_RELAXED, __HIP_MEMORY_SCOPE_AGENT);
    } else {
      for (int it = 0; it < 64; ++it){
        if (__hip_atomic_load(&ctrl[32], __ATOMIC_RELAXED, __HIP_MEMORY_SCOPE_AGENT) >= SNBLK) break;
        for (int j = 0; j < 4; ++j) __builtin_amdgcn_s_sleep(32);
      }
      if (__hip_atomic_load(&ctrl[32], __ATOMIC_RELAXED, __HIP_MEMORY_SCOPE_AGENT) < SNBLK)
        ticket = __hip_atomic_fetch_add(&ctrl[32], 1, __ATOMIC_RELAXED, __HIP_MEMORY_SCOPE_AGENT);
    }
    int slot = (ticket >= 0 && ticket < SNBLK) ? ticket : -1;
    int fast = 1;
    if (slot >= 0){
      // zero my step-flag with a PLAIN (workgroup-scope) store -> corrects the
      // shared-L2 line itself (safe vs stale cross-replay lines), then publish
      // (agent release also pushes it toward IC for the slow path).
      __hip_atomic_store(&ctrl[FB + slot*32], 0, __ATOMIC_RELAXED, __HIP_MEMORY_SCOPE_WORKGROUP);
      __hip_atomic_store(&ctrl[PB + slot], xcc + 1, __ATOMIC_RELEASE, __HIP_MEMORY_SCOPE_AGENT);
      for (int i = 0; i < SNBLK; ++i){
        int v;
        while ((v = __hip_atomic_load(&ctrl[PB + i], __ATOMIC_ACQUIRE, __HIP_MEMORY_SCOPE_AGENT)) == 0)
          __builtin_amdgcn_s_sleep(8);
        if (v - 1 != xcc) fast = 0;   // any worker off-XCD -> slow (agent) protocol
      }
    }
    s_slot = slot; s_fast = fast;
  }
  __syncthreads();
  const int slot = s_slot, fastp = s_fast;
  if (slot < 0) return;
  const int n0 = slot * 64;

  const int kh = wid >> 1, ch = wid & 1;     // wave = (K-half, col-half)
  const int la = lane & 15, kg = lane >> 4;
  const int b  = tid >> 3, nn = (tid & 7) * 8;  // gate-math ownership: (batch, 8 cols)

  // ---- preload U^T B-fragments into registers (held for all 256 steps) ----
  short8 Br0[16], Br1[16];
  {
    const unsigned short* u0 = UT + (size_t)(n0 + ch*32 + la) * HID + kh*512 + kg*8;
    const unsigned short* u1 = u0 + (size_t)16 * HID;
    #pragma unroll
    for (int kc = 0; kc < 16; ++kc){
      Br0[kc] = *(const short8*)(u0 + kc*32);
      Br1[kc] = *(const short8*)(u1 + kc*32);
    }
  }
  float c[8];
  #pragma unroll
  for (int j = 0; j < 8; ++j) c[j] = 0.f;
  float g0r[8];
  {
    const float* gp = G0 + (size_t)b * HID + n0 + nn;
    float4 lo = *(const float4*)gp, hi = *(const float4*)(gp + 4);
    g0r[0]=lo.x; g0r[1]=lo.y; g0r[2]=lo.z; g0r[3]=lo.w;
    g0r[4]=hi.x; g0r[5]=hi.y; g0r[6]=hi.z; g0r[7]=hi.w;
  }

  for (int t = 0; t < SEQ; ++t){
    // ---- h_{t-1} @ U (this wave: its K-half x its col-half) ----
    const unsigned short* hp = Hfull + (size_t)t * 32 * HID + kh*512 + kg*8;
    short8 A0[16], A1[16];
    #pragma unroll
    for (int kc = 0; kc < 16; ++kc){
      A0[kc] = *(const short8*)(hp + (size_t)la * HID + kc*32);
      A1[kc] = *(const short8*)(hp + (size_t)(16 + la) * HID + kc*32);
    }
    f32x4 a00 = {0,0,0,0}, a01 = {0,0,0,0}, a10 = {0,0,0,0}, a11 = {0,0,0,0};
    #pragma unroll
    for (int kc = 0; kc < 16; ++kc){
      a00 = __builtin_amdgcn_mfma_f32_16x16x32_bf16(A0[kc], Br0[kc], a00, 0, 0, 0);
      a01 = __builtin_amdgcn_mfma_f32_16x16x32_bf16(A0[kc], Br1[kc], a01, 0, 0, 0);
      a10 = __builtin_amdgcn_mfma_f32_16x16x32_bf16(A1[kc], Br0[kc], a10, 0, 0, 0);
      a11 = __builtin_amdgcn_mfma_f32_16x16x32_bf16(A1[kc], Br1[kc], a11, 0, 0, 0);
    }
    #pragma unroll
    for (int rg = 0; rg < 4; ++rg){
      red[kh][kg*4 + rg][ch*32 + la]           = a00[rg];
      red[kh][kg*4 + rg][ch*32 + 16 + la]      = a01[rg];
      red[kh][16 + kg*4 + rg][ch*32 + la]      = a10[rg];
      red[kh][16 + kg*4 + rg][ch*32 + 16 + la] = a11[rg];
    }
    __syncthreads();

    // ---- gates + h-write (plain stores -> this XCD's L2) ----
    short8 hv;
    #pragma unroll
    for (int j = 0; j < 8; ++j){
      float g  = red[0][b][nn + j] + red[1][b][nn + j] + g0r[j];
      float s  = 1.f / (1.f + __expf(-g));
      float tg = 1.f - 2.f / (__expf(2.f*g) + 1.f);
      float cn = s * (c[j] + tg);
      c[j] = cn;
      float hn = (1.f - 2.f / (__expf(2.f*cn) + 1.f)) * s;
      hv[j] = (short)f2bf(hn);
    }
    *(short8*)(Hfull + ((size_t)(t+1)*32 + b) * HID + n0 + nn) = hv;

    if (t + 1 < SEQ){
      // prefetch next step's G0 BEFORE the barrier: the barrier's vmcnt(0)
      // drains it, so the poll loop below has zero outstanding vmem.
      {
        const float* gp = G0 + ((size_t)(t+1)*32 + b) * HID + n0 + nn;
        float4 lo = *(const float4*)gp, hi = *(const float4*)(gp + 4);
        g0r[0]=lo.x; g0r[1]=lo.y; g0r[2]=lo.z; g0r[3]=lo.w;
        g0r[4]=hi.x; g0r[5]=hi.y; g0r[6]=hi.z; g0r[7]=hi.w;
      }
      __syncthreads();                  // drains all waves' h-stores before flag
      if (fastp){
        if (tid == 0)                   // plain store -> lands in shared L2
          __hip_atomic_store(&ctrl[FB + slot*32], t + 1, __ATOMIC_RELAXED, __HIP_MEMORY_SCOPE_WORKGROUP);
        const int* fp = &ctrl[FB + (lane & 15) * 32];
        int guard = 0;
        for (;;){
          int v = load_flag_sc0(fp);    // sc0: L1-bypass, L2-hit
          if (__all(v >= t + 1)) break;
          if (++guard > (1<<12)) break; // deadman: visible failure > hang
        }
      } else {
        if (tid == 0){
          __threadfence();              // wbl2: publish h to IC
          __hip_atomic_store(&ctrl[FB + slot*32], t + 1, __ATOMIC_RELAXED, __HIP_MEMORY_SCOPE_AGENT);
        }
        const int fi = FB + (lane & 15) * 32;
        int guard = 0;
        for (;;){
          int v = __hip_atomic_load(&ctrl[fi], __ATOMIC_RELAXED, __HIP_MEMORY_SCOPE_AGENT);
          if (__all(v >= t + 1)) break;
          if (++guard > (1<<14)) break;
          __builtin_amdgcn_s_sleep(4);
        }
        __threadfence();                // inv: drop stale L2 before reading remote h
      }
    }
  }

  // slow-path marker: +~1ms on worker 0 so dur_us tells us which path ran
  if (!fastp && slot == 0 && tid == 0){
    long long t0 = __builtin_amdgcn_s_memrealtime();   // ~100 MHz ref clock
    while (__builtin_amdgcn_s_memrealtime() - t0 < 100000LL) {}
  }
}

extern "C" void kernel_launch(void* const* d_in, const int* in_sizes, int n_in,
                              void* d_out, int out_size, void* d_ws, size_t ws_size,
                              hipStream_t stream){
  (void)in_sizes; (void)n_in; (void)out_size;
  const int*   seq     = (const int*)d_in[0];
  const float* emb     = (const float*)d_in[1];
  const float* w_gate  = (const float*)d_in[2];
  const float* b_gate  = (const float*)d_in[3];
  const float* w_out   = (const float*)d_in[4];
  const float* b_out   = (const float*)d_in[5];
  const float* w_dense = (const float*)d_in[6];
  const float* b_dense = (const float*)d_in[7];
  float* out = (float*)d_out;

  const int NPAD_D = 10112;   // 79 * 128
  char* ws = (char*)d_ws;
  size_t off = 0;
  auto alloc = [&](size_t bytes){ size_t o = off; off += (bytes + 255) & ~(size_t)255; return o; };
  size_t off_W1T = alloc((size_t)2*HID*HID);
  size_t off_UT  = alloc((size_t)2*HID*HID);
  size_t off_WoT = alloc((size_t)2*HID*HID);
  size_t off_WdT = alloc((size_t)2*NPAD_D*HID);
  size_t off_X   = alloc((size_t)2*ROWS*EMB);             // bf16; reused as YS
  size_t off_G0  = alloc((size_t)4*ROWS*HID);
  size_t off_H   = alloc((size_t)2*(ROWS+32)*HID);
  size_t off_ctl = alloc(8192);
  if (ws_size < off) return;

  unsigned short* W1T = (unsigned short*)(ws + off_W1T);
  unsigned short* UT  = (unsigned short*)(ws + off_UT);
  unsigned short* WoT = (unsigned short*)(ws + off_WoT);
  unsigned short* WdT = (unsigned short*)(ws + off_WdT);
  unsigned short* X   = (unsigned short*)(ws + off_X);
  unsigned short* YS  = (unsigned short*)(ws + off_X);
  float*          G0  = (float*)(ws + off_G0);
  unsigned short* Hf  = (unsigned short*)(ws + off_H);
  int*            ctl = (int*)(ws + off_ctl);

  hipMemsetAsync(ctl, 0, 8192, stream);
  hipMemsetAsync(WdT + (size_t)10000*HID, 0, (size_t)2*(NPAD_D-10000)*HID, stream);
  hipMemsetAsync(Hf, 0, (size_t)2*32*HID, stream);

  k_transpose<<<dim3(16,16), 256, 0, stream>>>(w_gate,           W1T, HID, HID);
  k_transpose<<<dim3(16,16), 256, 0, stream>>>(w_gate + HID*HID, UT,  HID, HID);
  k_transpose<<<dim3(16,16), 256, 0, stream>>>(w_out,            WoT, HID, HID);
  k_transpose<<<dim3(157,16),256, 0, stream>>>(w_dense,          WdT, HID, VOCAB);

  k_gather<<<ROWS, 256, 0, stream>>>(seq, emb, X);

  // G0 = X @ W1 + b_gate  (fp32 out)
  k_gemm_bt<false><<<dim3(8,64), 256, 0, stream>>>(X, W1T, b_gate, G0, ROWS, HID, EMB, HID);

  // sequential scan (16 workers elected from 256 candidate blocks)
  k_scan<<<256, 256, 0, stream>>>(UT, G0, Hf, ctl);

  // ys = H @ w_out + b_out  (bf16 out)
  k_gemm_bt<true><<<dim3(8,64), 256, 0, stream>>>(Hf + (size_t)32*HID, WoT, b_out, YS,
                                                  ROWS, HID, HID, HID);

  // logits = ys @ w_dense + b_dense (fp32 out)
  k_gemm_bt<false><<<dim3(79,64), 256, 0, stream>>>(YS, WdT, b_dense, out,
                                                    ROWS, VOCAB, HID, VOCAB);
}

// Round 5
// 4223.673 us; speedup vs baseline: 26.5912x; 26.5912x over previous
//
#include <hip/hip_runtime.h>
#include <hip/hip_bf16.h>
#include <cstdint>
#include <cstddef>

#define VOCAB 10000
#define EMB   1024
#define HID   1024
#define BATCH 32
#define SEQ   256
#define ROWS  (SEQ*BATCH)   // 8192
#define SNBLK 16            // scan workers; 64 cols each
#define PB    128           // ctrl: published-xcc base (ints)
#define FB    1024          // ctrl: step-flag base (ints), stride 32

typedef __attribute__((ext_vector_type(8))) short short8;
typedef __attribute__((ext_vector_type(4))) float f32x4;

static __device__ __forceinline__ unsigned short f2bf(float f){
  unsigned int u = __builtin_bit_cast(unsigned int, f);
  u += 0x7fffu + ((u >> 16) & 1u);
  return (unsigned short)(u >> 16);
}

// ---------- transpose-convert: fp32 src[K][N] -> bf16 dst[N][K] ----------
__global__ void k_transpose(const float* __restrict__ src, unsigned short* __restrict__ dst,
                            int K, int N){
  __shared__ unsigned short tile[64][65];
  int n0 = blockIdx.x * 64, k0 = blockIdx.y * 64;
  int tid = threadIdx.x;
  #pragma unroll
  for (int it = 0; it < 16; ++it){
    int e = tid + it*256;
    int i = e >> 6, j = e & 63;
    float v = 0.f;
    if (k0 + i < K && n0 + j < N) v = src[(size_t)(k0+i)*N + n0 + j];
    tile[j][i] = f2bf(v);
  }
  __syncthreads();
  #pragma unroll
  for (int it = 0; it < 16; ++it){
    int e = tid + it*256;
    int r = e >> 6, c = e & 63;
    if (n0 + r < N && k0 + c < K)
      dst[(size_t)(n0+r)*K + k0 + c] = tile[r][c];
  }
}

// ---------- embedding gather + fp32->bf16 ----------
__global__ void k_gather(const int* __restrict__ seq, const float* __restrict__ emb,
                         unsigned short* __restrict__ X){
  int r = blockIdx.x;                 // r = t*32 + b
  int t = r >> 5, b = r & 31;
  int idx = seq[b*SEQ + t];
  const float4* s = (const float4*)(emb + (size_t)idx * EMB);
  float4 v = s[threadIdx.x];
  ushort4 o;
  o.x = f2bf(v.x); o.y = f2bf(v.y); o.z = f2bf(v.z); o.w = f2bf(v.w);
  ((ushort4*)(X + (size_t)r * EMB))[threadIdx.x] = o;
}

// ---------- GEMM: C[M][ldc] = A[M][K](bf16) * BT[Npad][K](bf16)^T + bias ----------
template<bool OUT_BF16>
__global__ __launch_bounds__(256) void k_gemm_bt(
    const unsigned short* __restrict__ A,
    const unsigned short* __restrict__ BT,
    const float* __restrict__ bias,
    void* __restrict__ C, int M, int Nreal, int K, int ldc){
  __shared__ __align__(16) unsigned short As[128][40];
  __shared__ __align__(16) unsigned short Bs[128][40];
  int tid  = threadIdx.x;
  int lane = tid & 63, wid = tid >> 6;
  int wr = (wid >> 1) * 64, wc = (wid & 1) * 64;
  int m0 = blockIdx.y * 128, n0 = blockIdx.x * 128;
  int la = lane & 15, ko = (lane >> 4) * 8;
  f32x4 acc[4][4] = {};
  for (int k0 = 0; k0 < K; k0 += 32){
    #pragma unroll
    for (int q = tid; q < 512; q += 256){
      int row = q >> 2, kc = (q & 3) * 8;
      *(uint4*)&As[row][kc] = *(const uint4*)(A  + (size_t)(m0+row)*K + k0 + kc);
      *(uint4*)&Bs[row][kc] = *(const uint4*)(BT + (size_t)(n0+row)*K + k0 + kc);
    }
    __syncthreads();
    short8 av[4], bv[4];
    #pragma unroll
    for (int f = 0; f < 4; ++f){
      av[f] = *(const short8*)&As[wr + f*16 + la][ko];
      bv[f] = *(const short8*)&Bs[wc + f*16 + la][ko];
    }
    #pragma unroll
    for (int mf = 0; mf < 4; ++mf)
      #pragma unroll
      for (int nf = 0; nf < 4; ++nf)
        acc[mf][nf] = __builtin_amdgcn_mfma_f32_16x16x32_bf16(av[mf], bv[nf], acc[mf][nf], 0, 0, 0);
    __syncthreads();
  }
  int dr = (lane >> 4) * 4, dc = lane & 15;
  #pragma unroll
  for (int mf = 0; mf < 4; ++mf){
    #pragma unroll
    for (int nf = 0; nf < 4; ++nf){
      int col = n0 + wc + nf*16 + dc;
      if (col >= Nreal) continue;
      float bb = bias[col];
      #pragma unroll
      for (int rg = 0; rg < 4; ++rg){
        int row = m0 + wr + mf*16 + dr + rg;
        float v = acc[mf][nf][rg] + bb;
        if (OUT_BF16) ((unsigned short*)C)[(size_t)row*ldc + col] = f2bf(v);
        else          ((float*)C)[(size_t)row*ldc + col] = v;
      }
    }
  }
}

// ---------- ablation scan: identical compute core, NO synchronization ----------
// 16 blocks, dummy H (4128 rows, t&127 wrap). Its rocprof dur = compute floor.
__global__ __launch_bounds__(256, 1) void k_scanv(
    const unsigned short* __restrict__ UT,
    const float* __restrict__ G0,
    unsigned short* __restrict__ Hd){
  __shared__ float red[2][32][64];
  const int tid  = threadIdx.x;
  const int lane = tid & 63, wid = tid >> 6;
  const int n0 = blockIdx.x * 64;
  const int kh = wid >> 1, ch = wid & 1;
  const int la = lane & 15, kg = lane >> 4;
  const int b  = tid >> 3, nn = (tid & 7) * 8;

  short8 Br0[16], Br1[16];
  {
    const unsigned short* u0 = UT + (size_t)(n0 + ch*32 + la) * HID + kh*512 + kg*8;
    const unsigned short* u1 = u0 + (size_t)16 * HID;
    #pragma unroll
    for (int kc = 0; kc < 16; ++kc){
      Br0[kc] = *(const short8*)(u0 + kc*32);
      Br1[kc] = *(const short8*)(u1 + kc*32);
    }
  }
  float c[8];
  #pragma unroll
  for (int j = 0; j < 8; ++j) c[j] = 0.f;
  float g0r[8];
  {
    const float* gp = G0 + (size_t)b * HID + n0 + nn;
    float4 lo = *(const float4*)gp, hi = *(const float4*)(gp + 4);
    g0r[0]=lo.x; g0r[1]=lo.y; g0r[2]=lo.z; g0r[3]=lo.w;
    g0r[4]=hi.x; g0r[5]=hi.y; g0r[6]=hi.z; g0r[7]=hi.w;
  }

  for (int t = 0; t < SEQ; ++t){
    const unsigned short* hp = Hd + (size_t)(t & 127) * 32 * HID + kh*512 + kg*8;
    short8 A0[16], A1[16];
    #pragma unroll
    for (int kc = 0; kc < 16; ++kc){
      A0[kc] = *(const short8*)(hp + (size_t)la * HID + kc*32);
      A1[kc] = *(const short8*)(hp + (size_t)(16 + la) * HID + kc*32);
    }
    f32x4 a00 = {0,0,0,0}, a01 = {0,0,0,0}, a10 = {0,0,0,0}, a11 = {0,0,0,0};
    #pragma unroll
    for (int kc = 0; kc < 16; ++kc){
      a00 = __builtin_amdgcn_mfma_f32_16x16x32_bf16(A0[kc], Br0[kc], a00, 0, 0, 0);
      a01 = __builtin_amdgcn_mfma_f32_16x16x32_bf16(A0[kc], Br1[kc], a01, 0, 0, 0);
      a10 = __builtin_amdgcn_mfma_f32_16x16x32_bf16(A1[kc], Br0[kc], a10, 0, 0, 0);
      a11 = __builtin_amdgcn_mfma_f32_16x16x32_bf16(A1[kc], Br1[kc], a11, 0, 0, 0);
    }
    #pragma unroll
    for (int rg = 0; rg < 4; ++rg){
      red[kh][kg*4 + rg][ch*32 + la]           = a00[rg];
      red[kh][kg*4 + rg][ch*32 + 16 + la]      = a01[rg];
      red[kh][16 + kg*4 + rg][ch*32 + la]      = a10[rg];
      red[kh][16 + kg*4 + rg][ch*32 + 16 + la] = a11[rg];
    }
    __syncthreads();
    short8 hv;
    #pragma unroll
    for (int j = 0; j < 8; ++j){
      float g  = red[0][b][nn + j] + red[1][b][nn + j] + g0r[j];
      float s  = 1.f / (1.f + __expf(-g));
      float tg = 1.f - 2.f / (__expf(2.f*g) + 1.f);
      float cn = s * (c[j] + tg);
      c[j] = cn;
      float hn = (1.f - 2.f / (__expf(2.f*cn) + 1.f)) * s;
      hv[j] = (short)f2bf(hn);
    }
    *(short8*)(Hd + ((size_t)((t & 127) + 1)*32 + b) * HID + n0 + nn) = hv;
    if (t + 1 < SEQ){
      const float* gp = G0 + ((size_t)(t+1)*32 + b) * HID + n0 + nn;
      float4 lo = *(const float4*)gp, hi = *(const float4*)(gp + 4);
      g0r[0]=lo.x; g0r[1]=lo.y; g0r[2]=lo.z; g0r[3]=lo.w;
      g0r[4]=hi.x; g0r[5]=hi.y; g0r[6]=hi.z; g0r[7]=hi.w;
      __syncthreads();     // intra-block only; NO cross-block sync at all
    }
  }
}

// ---------- real scan: 16 workers elected onto ONE XCD ----------
// fast path: fence-free (h via shared L2) + agent-atomic flags (IC, proven channel)
// slow path: round-3 fenced protocol. Telemetry: slow=+1ms, deadman=+4ms spin.
__global__ __launch_bounds__(256, 1) void k_scan(
    const unsigned short* __restrict__ UT,
    const float* __restrict__ G0,
    unsigned short* __restrict__ Hfull,
    int* ctrl){
  __shared__ float red[2][32][64];
  __shared__ int s_slot, s_fast;
  const int tid  = threadIdx.x;
  const int lane = tid & 63, wid = tid >> 6;

  if (tid == 0){
    int xcc;
    asm volatile("s_getreg_b32 %0, hwreg(HW_REG_XCC_ID)" : "=s"(xcc));
    xcc &= 0xff;
    int expected = 0;
    __hip_atomic_compare_exchange_strong(&ctrl[0], &expected, xcc + 1,
        __ATOMIC_ACQ_REL, __ATOMIC_ACQUIRE, __HIP_MEMORY_SCOPE_AGENT);
    int lead = (expected == 0) ? xcc : expected - 1;
    int ticket = -1;
    if (xcc == lead){
      ticket = __hip_atomic_fetch_add(&ctrl[32], 1, __ATOMIC_RELAXED, __HIP_MEMORY_SCOPE_AGENT);
    } else {
      for (int it = 0; it < 64; ++it){
        if (__hip_atomic_load(&ctrl[32], __ATOMIC_RELAXED, __HIP_MEMORY_SCOPE_AGENT) >= SNBLK) break;
        for (int j = 0; j < 4; ++j) __builtin_amdgcn_s_sleep(32);
      }
      if (__hip_atomic_load(&ctrl[32], __ATOMIC_RELAXED, __HIP_MEMORY_SCOPE_AGENT) < SNBLK)
        ticket = __hip_atomic_fetch_add(&ctrl[32], 1, __ATOMIC_RELAXED, __HIP_MEMORY_SCOPE_AGENT);
    }
    int slot = (ticket >= 0 && ticket < SNBLK) ? ticket : -1;
    int fast = 1;
    if (slot >= 0){
      __hip_atomic_store(&ctrl[PB + slot], xcc + 1, __ATOMIC_RELEASE, __HIP_MEMORY_SCOPE_AGENT);
      for (int i = 0; i < SNBLK; ++i){
        int v;
        while ((v = __hip_atomic_load(&ctrl[PB + i], __ATOMIC_ACQUIRE, __HIP_MEMORY_SCOPE_AGENT)) == 0)
          __builtin_amdgcn_s_sleep(8);
        if (v - 1 != xcc) fast = 0;
      }
    }
    s_slot = slot; s_fast = fast;
  }
  __syncthreads();
  const int slot = s_slot, fastp = s_fast;
  if (slot < 0) return;
  const int n0 = slot * 64;

  const int kh = wid >> 1, ch = wid & 1;
  const int la = lane & 15, kg = lane >> 4;
  const int b  = tid >> 3, nn = (tid & 7) * 8;

  short8 Br0[16], Br1[16];
  {
    const unsigned short* u0 = UT + (size_t)(n0 + ch*32 + la) * HID + kh*512 + kg*8;
    const unsigned short* u1 = u0 + (size_t)16 * HID;
    #pragma unroll
    for (int kc = 0; kc < 16; ++kc){
      Br0[kc] = *(const short8*)(u0 + kc*32);
      Br1[kc] = *(const short8*)(u1 + kc*32);
    }
  }
  float c[8];
  #pragma unroll
  for (int j = 0; j < 8; ++j) c[j] = 0.f;
  float g0r[8];
  {
    const float* gp = G0 + (size_t)b * HID + n0 + nn;
    float4 lo = *(const float4*)gp, hi = *(const float4*)(gp + 4);
    g0r[0]=lo.x; g0r[1]=lo.y; g0r[2]=lo.z; g0r[3]=lo.w;
    g0r[4]=hi.x; g0r[5]=hi.y; g0r[6]=hi.z; g0r[7]=hi.w;
  }

  int deadman = 0;

  for (int t = 0; t < SEQ; ++t){
    const unsigned short* hp = Hfull + (size_t)t * 32 * HID + kh*512 + kg*8;
    short8 A0[16], A1[16];
    #pragma unroll
    for (int kc = 0; kc < 16; ++kc){
      A0[kc] = *(const short8*)(hp + (size_t)la * HID + kc*32);
      A1[kc] = *(const short8*)(hp + (size_t)(16 + la) * HID + kc*32);
    }
    f32x4 a00 = {0,0,0,0}, a01 = {0,0,0,0}, a10 = {0,0,0,0}, a11 = {0,0,0,0};
    #pragma unroll
    for (int kc = 0; kc < 16; ++kc){
      a00 = __builtin_amdgcn_mfma_f32_16x16x32_bf16(A0[kc], Br0[kc], a00, 0, 0, 0);
      a01 = __builtin_amdgcn_mfma_f32_16x16x32_bf16(A0[kc], Br1[kc], a01, 0, 0, 0);
      a10 = __builtin_amdgcn_mfma_f32_16x16x32_bf16(A1[kc], Br0[kc], a10, 0, 0, 0);
      a11 = __builtin_amdgcn_mfma_f32_16x16x32_bf16(A1[kc], Br1[kc], a11, 0, 0, 0);
    }
    #pragma unroll
    for (int rg = 0; rg < 4; ++rg){
      red[kh][kg*4 + rg][ch*32 + la]           = a00[rg];
      red[kh][kg*4 + rg][ch*32 + 16 + la]      = a01[rg];
      red[kh][16 + kg*4 + rg][ch*32 + la]      = a10[rg];
      red[kh][16 + kg*4 + rg][ch*32 + 16 + la] = a11[rg];
    }
    __syncthreads();

    short8 hv;
    #pragma unroll
    for (int j = 0; j < 8; ++j){
      float g  = red[0][b][nn + j] + red[1][b][nn + j] + g0r[j];
      float s  = 1.f / (1.f + __expf(-g));
      float tg = 1.f - 2.f / (__expf(2.f*g) + 1.f);
      float cn = s * (c[j] + tg);
      c[j] = cn;
      float hn = (1.f - 2.f / (__expf(2.f*cn) + 1.f)) * s;
      hv[j] = (short)f2bf(hn);
    }
    *(short8*)(Hfull + ((size_t)(t+1)*32 + b) * HID + n0 + nn) = hv;

    if (t + 1 < SEQ){
      { // G0 prefetch BEFORE barrier (barrier's vmcnt(0) drains it)
        const float* gp = G0 + ((size_t)(t+1)*32 + b) * HID + n0 + nn;
        float4 lo = *(const float4*)gp, hi = *(const float4*)(gp + 4);
        g0r[0]=lo.x; g0r[1]=lo.y; g0r[2]=lo.z; g0r[3]=lo.w;
        g0r[4]=hi.x; g0r[5]=hi.y; g0r[6]=hi.z; g0r[7]=hi.w;
      }
      __syncthreads();   // all waves' h-stores are in L2 before the flag goes out
      if (tid == 0){
        if (!fastp) __threadfence();   // slow path: wbL2 -> publish h to IC
        __hip_atomic_store(&ctrl[FB + slot*32], t + 1, __ATOMIC_RELAXED, __HIP_MEMORY_SCOPE_AGENT);
      }
      if (tid < 64){                   // ONLY wave 0 polls (avoid IC poller storm)
        const int fi = FB + (lane & 15) * 32;
        int guard = 0;
        for (;;){
          int v = __hip_atomic_load(&ctrl[fi], __ATOMIC_RELAXED, __HIP_MEMORY_SCOPE_AGENT);
          if (__all(v >= t + 1)) break;
          if (++guard > (1<<12)) { deadman = 1; break; }
          __builtin_amdgcn_s_sleep(1);
        }
        if (!fastp && lane == 0) __threadfence();  // slow path acquire
      }
      __syncthreads();
    }
  }

  // telemetry (burns time only on failure paths, visible in dur_us)
  if (tid < 64 && __any(deadman) && lane == 0)
    __hip_atomic_fetch_or(&ctrl[64], 1, __ATOMIC_RELAXED, __HIP_MEMORY_SCOPE_AGENT);
  if (slot == 0 && tid == 0){
    long long spin = 0;
    if (!fastp) spin += 100000LL;      // +1 ms: slow path ran
    if (__hip_atomic_load(&ctrl[64], __ATOMIC_RELAXED, __HIP_MEMORY_SCOPE_AGENT) != 0)
      spin += 400000LL;                // +4 ms: some deadman fired
    if (spin){
      long long t0 = __builtin_amdgcn_s_memrealtime();
      while (__builtin_amdgcn_s_memrealtime() - t0 < spin) {}
    }
  }
}

extern "C" void kernel_launch(void* const* d_in, const int* in_sizes, int n_in,
                              void* d_out, int out_size, void* d_ws, size_t ws_size,
                              hipStream_t stream){
  (void)in_sizes; (void)n_in; (void)out_size;
  const int*   seq     = (const int*)d_in[0];
  const float* emb     = (const float*)d_in[1];
  const float* w_gate  = (const float*)d_in[2];
  const float* b_gate  = (const float*)d_in[3];
  const float* w_out   = (const float*)d_in[4];
  const float* b_out   = (const float*)d_in[5];
  const float* w_dense = (const float*)d_in[6];
  const float* b_dense = (const float*)d_in[7];
  float* out = (float*)d_out;

  const int NPAD_D = 10112;   // 79 * 128
  char* ws = (char*)d_ws;
  size_t off = 0;
  auto alloc = [&](size_t bytes){ size_t o = off; off += (bytes + 255) & ~(size_t)255; return o; };
  size_t off_W1T = alloc((size_t)2*HID*HID);
  size_t off_UT  = alloc((size_t)2*HID*HID);
  size_t off_WoT = alloc((size_t)2*HID*HID);
  size_t off_WdT = alloc((size_t)2*NPAD_D*HID);
  size_t off_X   = alloc((size_t)2*ROWS*EMB);             // bf16; reused: ablation-H, then YS
  size_t off_G0  = alloc((size_t)4*ROWS*HID);
  size_t off_H   = alloc((size_t)2*(ROWS+32)*HID);
  size_t off_ctl = alloc(8192);
  if (ws_size < off) return;

  unsigned short* W1T = (unsigned short*)(ws + off_W1T);
  unsigned short* UT  = (unsigned short*)(ws + off_UT);
  unsigned short* WoT = (unsigned short*)(ws + off_WoT);
  unsigned short* WdT = (unsigned short*)(ws + off_WdT);
  unsigned short* X   = (unsigned short*)(ws + off_X);
  unsigned short* YS  = (unsigned short*)(ws + off_X);
  unsigned short* Hd  = (unsigned short*)(ws + off_X);    // ablation dummy H (8.5MB < 16.8MB)
  float*          G0  = (float*)(ws + off_G0);
  unsigned short* Hf  = (unsigned short*)(ws + off_H);
  int*            ctl = (int*)(ws + off_ctl);

  hipMemsetAsync(ctl, 0, 8192, stream);
  hipMemsetAsync(WdT + (size_t)10000*HID, 0, (size_t)2*(NPAD_D-10000)*HID, stream);
  hipMemsetAsync(Hf, 0, (size_t)2*32*HID, stream);

  k_transpose<<<dim3(16,16), 256, 0, stream>>>(w_gate,           W1T, HID, HID);
  k_transpose<<<dim3(16,16), 256, 0, stream>>>(w_gate + HID*HID, UT,  HID, HID);
  k_transpose<<<dim3(16,16), 256, 0, stream>>>(w_out,            WoT, HID, HID);
  k_transpose<<<dim3(157,16),256, 0, stream>>>(w_dense,          WdT, HID, VOCAB);

  k_gather<<<ROWS, 256, 0, stream>>>(seq, emb, X);

  // G0 = X @ W1 + b_gate  (fp32 out)
  k_gemm_bt<false><<<dim3(8,64), 256, 0, stream>>>(X, W1T, b_gate, G0, ROWS, HID, EMB, HID);

  // ablation: sync-free scan clone into dummy H (X region is dead now) -> compute floor
  k_scanv<<<SNBLK, 256, 0, stream>>>(UT, G0, Hd);

  // real sequential scan
  k_scan<<<256, 256, 0, stream>>>(UT, G0, Hf, ctl);

  // ys = H @ w_out + b_out  (bf16 out, into X region)
  k_gemm_bt<true><<<dim3(8,64), 256, 0, stream>>>(Hf + (size_t)32*HID, WoT, b_out, YS,
                                                  ROWS, HID, HID, HID);

  // logits = ys @ w_dense + b_dense (fp32 out)
  k_gemm_bt<false><<<dim3(79,64), 256, 0, stream>>>(YS, WdT, b_dense, out,
                                                    ROWS, VOCAB, HID, VOCAB);
}

// Round 6
// 2429.289 us; speedup vs baseline: 46.2326x; 1.7386x over previous
//
#include <hip/hip_runtime.h>
#include <hip/hip_bf16.h>
#include <cstdint>
#include <cstddef>

#define VOCAB 10000
#define EMB   1024
#define HID   1024
#define BATCH 32
#define SEQ   256
#define ROWS  (SEQ*BATCH)   // 8192
#define SNBLK 16            // scan workers; 64 cols each
#define PB    128           // ctrl: published-xcc base (ints)
#define FB    1024          // ctrl: step-flag base (ints), stride 64

typedef __attribute__((ext_vector_type(8))) short short8;
typedef __attribute__((ext_vector_type(4))) float f32x4;

static __device__ __forceinline__ unsigned short f2bf(float f){
  unsigned int u = __builtin_bit_cast(unsigned int, f);
  u += 0x7fffu + ((u >> 16) & 1u);
  return (unsigned short)(u >> 16);
}

// ---------- transpose-convert: fp32 src[K][N] -> bf16 dst[N][K] ----------
__global__ void k_transpose(const float* __restrict__ src, unsigned short* __restrict__ dst,
                            int K, int N){
  __shared__ unsigned short tile[64][65];
  int n0 = blockIdx.x * 64, k0 = blockIdx.y * 64;
  int tid = threadIdx.x;
  #pragma unroll
  for (int it = 0; it < 16; ++it){
    int e = tid + it*256;
    int i = e >> 6, j = e & 63;
    float v = 0.f;
    if (k0 + i < K && n0 + j < N) v = src[(size_t)(k0+i)*N + n0 + j];
    tile[j][i] = f2bf(v);
  }
  __syncthreads();
  #pragma unroll
  for (int it = 0; it < 16; ++it){
    int e = tid + it*256;
    int r = e >> 6, c = e & 63;
    if (n0 + r < N && k0 + c < K)
      dst[(size_t)(n0+r)*K + k0 + c] = tile[r][c];
  }
}

// ---------- embedding gather + fp32->bf16 ----------
__global__ void k_gather(const int* __restrict__ seq, const float* __restrict__ emb,
                         unsigned short* __restrict__ X){
  int r = blockIdx.x;                 // r = t*32 + b
  int t = r >> 5, b = r & 31;
  int idx = seq[b*SEQ + t];
  const float4* s = (const float4*)(emb + (size_t)idx * EMB);
  float4 v = s[threadIdx.x];
  ushort4 o;
  o.x = f2bf(v.x); o.y = f2bf(v.y); o.z = f2bf(v.z); o.w = f2bf(v.w);
  ((ushort4*)(X + (size_t)r * EMB))[threadIdx.x] = o;
}

// ---------- GEMM: C[M][ldc] = A[M][K](bf16) * BT[Npad][K](bf16)^T + bias ----------
template<bool OUT_BF16>
__global__ __launch_bounds__(256) void k_gemm_bt(
    const unsigned short* __restrict__ A,
    const unsigned short* __restrict__ BT,
    const float* __restrict__ bias,
    void* __restrict__ C, int M, int Nreal, int K, int ldc){
  __shared__ __align__(16) unsigned short As[128][40];
  __shared__ __align__(16) unsigned short Bs[128][40];
  int tid  = threadIdx.x;
  int lane = tid & 63, wid = tid >> 6;
  int wr = (wid >> 1) * 64, wc = (wid & 1) * 64;
  int m0 = blockIdx.y * 128, n0 = blockIdx.x * 128;
  int la = lane & 15, ko = (lane >> 4) * 8;
  f32x4 acc[4][4] = {};
  for (int k0 = 0; k0 < K; k0 += 32){
    #pragma unroll
    for (int q = tid; q < 512; q += 256){
      int row = q >> 2, kc = (q & 3) * 8;
      *(uint4*)&As[row][kc] = *(const uint4*)(A  + (size_t)(m0+row)*K + k0 + kc);
      *(uint4*)&Bs[row][kc] = *(const uint4*)(BT + (size_t)(n0+row)*K + k0 + kc);
    }
    __syncthreads();
    short8 av[4], bv[4];
    #pragma unroll
    for (int f = 0; f < 4; ++f){
      av[f] = *(const short8*)&As[wr + f*16 + la][ko];
      bv[f] = *(const short8*)&Bs[wc + f*16 + la][ko];
    }
    #pragma unroll
    for (int mf = 0; mf < 4; ++mf)
      #pragma unroll
      for (int nf = 0; nf < 4; ++nf)
        acc[mf][nf] = __builtin_amdgcn_mfma_f32_16x16x32_bf16(av[mf], bv[nf], acc[mf][nf], 0, 0, 0);
    __syncthreads();
  }
  int dr = (lane >> 4) * 4, dc = lane & 15;
  #pragma unroll
  for (int mf = 0; mf < 4; ++mf){
    #pragma unroll
    for (int nf = 0; nf < 4; ++nf){
      int col = n0 + wc + nf*16 + dc;
      if (col >= Nreal) continue;
      float bb = bias[col];
      #pragma unroll
      for (int rg = 0; rg < 4; ++rg){
        int row = m0 + wr + mf*16 + dr + rg;
        float v = acc[mf][nf][rg] + bb;
        if (OUT_BF16) ((unsigned short*)C)[(size_t)row*ldc + col] = f2bf(v);
        else          ((float*)C)[(size_t)row*ldc + col] = v;
      }
    }
  }
}

// ---------- persistent scan: 16 colocated workers; U in LDS; pipelined A-ring ----------
// Wave (kh,ch) = (K-half, col-half of the block's 64 cols). red: 2 K-partials.
__global__ __launch_bounds__(256, 1) void k_scan(
    const unsigned short* __restrict__ UT,   // [HID][HID] bf16, UT[n][k]
    const float* __restrict__ G0,            // [ROWS][HID] fp32 (includes b_gate)
    unsigned short* __restrict__ Hfull,      // [(32+ROWS)][HID] bf16, rows 0..31 zeroed
    int* ctrl){
  __shared__ __align__(16) unsigned short UTs[64*1024];  // 128 KB, swizzled
  __shared__ float red[2][32][64];                       // 16 KB
  __shared__ int s_slot, s_fast;
  const int tid  = threadIdx.x;
  const int lane = tid & 63, wid = tid >> 6;

  // ---- election (verbatim from round 5 — engaged fast path successfully) ----
  if (tid == 0){
    int xcc;
    asm volatile("s_getreg_b32 %0, hwreg(HW_REG_XCC_ID)" : "=s"(xcc));
    xcc &= 0xff;
    int expected = 0;
    __hip_atomic_compare_exchange_strong(&ctrl[0], &expected, xcc + 1,
        __ATOMIC_ACQ_REL, __ATOMIC_ACQUIRE, __HIP_MEMORY_SCOPE_AGENT);
    int lead = (expected == 0) ? xcc : expected - 1;
    int ticket = -1;
    if (xcc == lead){
      ticket = __hip_atomic_fetch_add(&ctrl[32], 1, __ATOMIC_RELAXED, __HIP_MEMORY_SCOPE_AGENT);
    } else {
      for (int it = 0; it < 64; ++it){
        if (__hip_atomic_load(&ctrl[32], __ATOMIC_RELAXED, __HIP_MEMORY_SCOPE_AGENT) >= SNBLK) break;
        for (int j = 0; j < 4; ++j) __builtin_amdgcn_s_sleep(32);
      }
      if (__hip_atomic_load(&ctrl[32], __ATOMIC_RELAXED, __HIP_MEMORY_SCOPE_AGENT) < SNBLK)
        ticket = __hip_atomic_fetch_add(&ctrl[32], 1, __ATOMIC_RELAXED, __HIP_MEMORY_SCOPE_AGENT);
    }
    int slot = (ticket >= 0 && ticket < SNBLK) ? ticket : -1;
    int fast = 1;
    if (slot >= 0){
      __hip_atomic_store(&ctrl[PB + slot], xcc + 1, __ATOMIC_RELEASE, __HIP_MEMORY_SCOPE_AGENT);
      for (int i = 0; i < SNBLK; ++i){
        int v;
        while ((v = __hip_atomic_load(&ctrl[PB + i], __ATOMIC_ACQUIRE, __HIP_MEMORY_SCOPE_AGENT)) == 0)
          __builtin_amdgcn_s_sleep(8);
        if (v - 1 != xcc) fast = 0;
      }
    }
    s_slot = slot; s_fast = fast;
  }
  __syncthreads();
  const int slot = s_slot, fastp = s_fast;
  if (slot < 0) return;
  const int n0 = slot * 64;

  // ---- U slice -> LDS, 16B-chunk XOR swizzle: chunk c of row r at (c ^ (r&7)) ----
  for (int i = tid; i < 8192; i += 256){
    int r = i >> 7, cc = i & 127;
    uint4 v = *(const uint4*)(UT + (size_t)(n0 + r)*HID + cc*8);
    *(uint4*)&UTs[r*1024 + ((cc ^ (r & 7)) * 8)] = v;
  }
  __syncthreads();

  const int kh = wid >> 1, ch = wid & 1;     // wave = (K-half, col-half)
  const int la = lane & 15, kg = lane >> 4;
  const int b  = tid >> 3, nn = (tid & 7) * 8;

  const int row0 = ch*32 + la, row1 = ch*32 + 16 + la;   // this wave's U rows (B cols)
  const unsigned short* ub0 = UTs + row0*1024;
  const unsigned short* ub1 = UTs + row1*1024;
  const int sw0 = row0 & 7, sw1 = row1 & 7;

  float creg[8];
  #pragma unroll
  for (int j = 0; j < 8; ++j) creg[j] = 0.f;
  float g0r[8];
  {
    const float* gp = G0 + (size_t)b * HID + n0 + nn;
    float4 lo = *(const float4*)gp, hi = *(const float4*)(gp + 4);
    g0r[0]=lo.x; g0r[1]=lo.y; g0r[2]=lo.z; g0r[3]=lo.w;
    g0r[4]=hi.x; g0r[5]=hi.y; g0r[6]=hi.z; g0r[7]=hi.w;
  }

  for (int t = 0; t < SEQ; ++t){
    // ---- wait for peers' h_{t-1} (skip own flag; all waves poll independently) ----
    if (t > 0){
      const int pi = lane & 15;
      const int* fp = &ctrl[FB + pi*64];
      int guard = 0, dead = 0;
      for (;;){
        int v = (pi == slot) ? 0x7fffffff
              : __hip_atomic_load(fp, __ATOMIC_RELAXED, __HIP_MEMORY_SCOPE_AGENT);
        if (__all(v >= t)) break;
        if (++guard > (1<<15)) { dead = 1; break; }
      }
      if (dead && lane == 0)
        __hip_atomic_fetch_or(&ctrl[64], 1, __ATOMIC_RELAXED, __HIP_MEMORY_SCOPE_AGENT);
      if (!fastp) __threadfence();   // slow path: invalidate L2 before remote h-read
    }

    // ---- h_{t-1} @ U : pipelined A-ring (8 deep, 64 VGPR in flight) ----
    const unsigned short* hp  = Hfull + (size_t)t*32*HID + kh*512 + kg*8;
    const unsigned short* hpA = hp + (size_t)la * HID;
    const unsigned short* hpB = hp + (size_t)(16 + la) * HID;
    short8 A0r[8], A1r[8];
    #pragma unroll
    for (int i = 0; i < 8; ++i){
      A0r[i] = *(const short8*)(hpA + i*32);
      A1r[i] = *(const short8*)(hpB + i*32);
    }
    f32x4 a00 = {0,0,0,0}, a01 = {0,0,0,0}, a10 = {0,0,0,0}, a11 = {0,0,0,0};
    #pragma unroll
    for (int kc = 0; kc < 16; ++kc){
      int cidx = (kh*16 + kc)*4 + kg;
      short8 b0 = *(const short8*)(ub0 + ((cidx ^ sw0) << 3));
      short8 b1 = *(const short8*)(ub1 + ((cidx ^ sw1) << 3));
      short8 a0 = A0r[kc & 7], a1 = A1r[kc & 7];
      if (kc < 8){   // refill ring slot for kc+8 (reuse distance = 8 iterations)
        A0r[kc] = *(const short8*)(hpA + (kc + 8)*32);
        A1r[kc] = *(const short8*)(hpB + (kc + 8)*32);
      }
      a00 = __builtin_amdgcn_mfma_f32_16x16x32_bf16(a0, b0, a00, 0, 0, 0);
      a01 = __builtin_amdgcn_mfma_f32_16x16x32_bf16(a0, b1, a01, 0, 0, 0);
      a10 = __builtin_amdgcn_mfma_f32_16x16x32_bf16(a1, b0, a10, 0, 0, 0);
      a11 = __builtin_amdgcn_mfma_f32_16x16x32_bf16(a1, b1, a11, 0, 0, 0);
    }
    #pragma unroll
    for (int rg = 0; rg < 4; ++rg){
      red[kh][kg*4 + rg][ch*32 + la]           = a00[rg];
      red[kh][kg*4 + rg][ch*32 + 16 + la]      = a01[rg];
      red[kh][16 + kg*4 + rg][ch*32 + la]      = a10[rg];
      red[kh][16 + kg*4 + rg][ch*32 + 16 + la] = a11[rg];
    }
    __syncthreads();

    // ---- gates (tanh = 2*sigma(2g)-1, exp(-2g)=e^2; v_rcp) + h-write ----
    short8 hv;
    #pragma unroll
    for (int j = 0; j < 8; ++j){
      float g  = red[0][b][nn + j] + red[1][b][nn + j] + g0r[j];
      float e  = __expf(-g);
      float s  = __builtin_amdgcn_rcpf(1.f + e);
      float e2 = e * e;
      float tg = 2.f * __builtin_amdgcn_rcpf(1.f + e2) - 1.f;
      float cn = s * (creg[j] + tg);
      creg[j] = cn;
      float ec = __expf(-2.f * cn);
      float th = 2.f * __builtin_amdgcn_rcpf(1.f + ec) - 1.f;
      hv[j] = (short)f2bf(th * s);
    }
    *(short8*)(Hfull + ((size_t)(t+1)*32 + b) * HID + n0 + nn) = hv;

    if (t + 1 < SEQ){   // G0 prefetch BEFORE barrier (barrier's vmcnt(0) drains it)
      const float* gp = G0 + ((size_t)(t+1)*32 + b) * HID + n0 + nn;
      float4 lo = *(const float4*)gp, hi = *(const float4*)(gp + 4);
      g0r[0]=lo.x; g0r[1]=lo.y; g0r[2]=lo.z; g0r[3]=lo.w;
      g0r[4]=hi.x; g0r[5]=hi.y; g0r[6]=hi.z; g0r[7]=hi.w;
    }
    __syncthreads();               // all waves' h-stores drained before flag
    if (tid == 0){
      if (!fastp) __threadfence(); // slow path: wbL2 -> publish h to IC
      __hip_atomic_store(&ctrl[FB + slot*64], t + 1, __ATOMIC_RELAXED, __HIP_MEMORY_SCOPE_AGENT);
    }
  }

  // telemetry: slow path +1ms, deadman +4ms (visible in dur_us)
  if (slot == 0 && tid == 0){
    long long spin = 0;
    if (!fastp) spin += 100000LL;
    if (__hip_atomic_load(&ctrl[64], __ATOMIC_RELAXED, __HIP_MEMORY_SCOPE_AGENT) != 0)
      spin += 400000LL;
    if (spin){
      long long t0 = __builtin_amdgcn_s_memrealtime();
      while (__builtin_amdgcn_s_memrealtime() - t0 < spin) {}
    }
  }
}

extern "C" void kernel_launch(void* const* d_in, const int* in_sizes, int n_in,
                              void* d_out, int out_size, void* d_ws, size_t ws_size,
                              hipStream_t stream){
  (void)in_sizes; (void)n_in; (void)out_size;
  const int*   seq     = (const int*)d_in[0];
  const float* emb     = (const float*)d_in[1];
  const float* w_gate  = (const float*)d_in[2];
  const float* b_gate  = (const float*)d_in[3];
  const float* w_out   = (const float*)d_in[4];
  const float* b_out   = (const float*)d_in[5];
  const float* w_dense = (const float*)d_in[6];
  const float* b_dense = (const float*)d_in[7];
  float* out = (float*)d_out;

  const int NPAD_D = 10112;   // 79 * 128
  char* ws = (char*)d_ws;
  size_t off = 0;
  auto alloc = [&](size_t bytes){ size_t o = off; off += (bytes + 255) & ~(size_t)255; return o; };
  size_t off_W1T = alloc((size_t)2*HID*HID);
  size_t off_UT  = alloc((size_t)2*HID*HID);
  size_t off_WoT = alloc((size_t)2*HID*HID);
  size_t off_WdT = alloc((size_t)2*NPAD_D*HID);
  size_t off_X   = alloc((size_t)2*ROWS*EMB);             // bf16; reused as YS
  size_t off_G0  = alloc((size_t)4*ROWS*HID);
  size_t off_H   = alloc((size_t)2*(ROWS+32)*HID);
  size_t off_ctl = alloc(8192);
  if (ws_size < off) return;

  unsigned short* W1T = (unsigned short*)(ws + off_W1T);
  unsigned short* UT  = (unsigned short*)(ws + off_UT);
  unsigned short* WoT = (unsigned short*)(ws + off_WoT);
  unsigned short* WdT = (unsigned short*)(ws + off_WdT);
  unsigned short* X   = (unsigned short*)(ws + off_X);
  unsigned short* YS  = (unsigned short*)(ws + off_X);
  float*          G0  = (float*)(ws + off_G0);
  unsigned short* Hf  = (unsigned short*)(ws + off_H);
  int*            ctl = (int*)(ws + off_ctl);

  hipMemsetAsync(ctl, 0, 8192, stream);
  hipMemsetAsync(WdT + (size_t)10000*HID, 0, (size_t)2*(NPAD_D-10000)*HID, stream);
  hipMemsetAsync(Hf, 0, (size_t)2*32*HID, stream);

  k_transpose<<<dim3(16,16), 256, 0, stream>>>(w_gate,           W1T, HID, HID);
  k_transpose<<<dim3(16,16), 256, 0, stream>>>(w_gate + HID*HID, UT,  HID, HID);
  k_transpose<<<dim3(16,16), 256, 0, stream>>>(w_out,            WoT, HID, HID);
  k_transpose<<<dim3(157,16),256, 0, stream>>>(w_dense,          WdT, HID, VOCAB);

  k_gather<<<ROWS, 256, 0, stream>>>(seq, emb, X);

  // G0 = X @ W1 + b_gate  (fp32 out)
  k_gemm_bt<false><<<dim3(8,64), 256, 0, stream>>>(X, W1T, b_gate, G0, ROWS, HID, EMB, HID);

  // sequential scan (16 workers elected from 256 candidate blocks)
  k_scan<<<256, 256, 0, stream>>>(UT, G0, Hf, ctl);

  // ys = H @ w_out + b_out  (bf16 out, into X region)
  k_gemm_bt<true><<<dim3(8,64), 256, 0, stream>>>(Hf + (size_t)32*HID, WoT, b_out, YS,
                                                  ROWS, HID, HID, HID);

  // logits = ys @ w_dense + b_dense (fp32 out)
  k_gemm_bt<false><<<dim3(79,64), 256, 0, stream>>>(YS, WdT, b_dense, out,
                                                    ROWS, VOCAB, HID, VOCAB);
}